// Round 1
// baseline (392.097 us; speedup 1.0000x reference)
//
#include <hip/hip_runtime.h>

#define CMID 32
#define CIN 128
#define HNB 32
#define KP 15
#define NEG 0.1f
#define EPS 1e-5f

// ---------------------------------------------------------------------------
// K1: y1 = s_feats @ w_u1  (M x 128 @ 128 x 32), plus per-channel sum/sumsq
// stats (for BN over the M axis) via block partials + atomics.
// ---------------------------------------------------------------------------
__global__ __launch_bounds__(256) void k1_gemm1(
    const float* __restrict__ A,   // s_feats (M,128)
    const float* __restrict__ B,   // w_u1 (128,32)
    float* __restrict__ y1,        // (M,32)
    float* __restrict__ st,        // stats: [0:32) sum, [32:64) sumsq
    int M)
{
    __shared__ float Bs[CIN * CMID];   // 16 KB
    __shared__ float As[32 * CIN];     // 16 KB
    __shared__ float red[256];
    int t = threadIdx.x;
    for (int i = t; i < CIN * CMID; i += 256) Bs[i] = B[i];
    int m0 = blockIdx.x * 32;
    int rows = min(32, M - m0);
    for (int i = t; i < rows * CIN; i += 256) As[i] = A[(size_t)m0 * CIN + i];
    __syncthreads();

    float sum = 0.f, sq = 0.f;
    int c = t & 31;
#pragma unroll
    for (int i = 0; i < 4; ++i) {
        int p = t + i * 256;
        int r = p >> 5;             // channel = p & 31 == c (256 % 32 == 0)
        if (r < rows) {
            float acc = 0.f;
#pragma unroll 8
            for (int j = 0; j < CIN; ++j) acc += As[r * CIN + j] * Bs[j * CMID + c];
            y1[(size_t)(m0 + r) * CMID + c] = acc;
            sum += acc; sq += acc * acc;
        }
    }
    red[t] = sum; __syncthreads();
    if (t < 32) { float s = 0.f; for (int i = 0; i < 8; ++i) s += red[t + 32 * i]; atomicAdd(&st[t], s); }
    __syncthreads();
    red[t] = sq; __syncthreads();
    if (t < 32) { float s = 0.f; for (int i = 0; i < 8; ++i) s += red[t + 32 * i]; atomicAdd(&st[32 + t], s); }
}

// ---------------------------------------------------------------------------
// K3: KPInv conv. One wave per point. lane = part*32 + h:
//   part selects channels [part*16, part*16+16), h is the neighbor.
// Applies unary1's BN+lrelu on the fly to the gathered y1 rows.
// out[m, g*16+cc] = sum_h nfeat[h,cc] * (sum_k infl[h,k]*w[m,k,g])
// ---------------------------------------------------------------------------
__global__ __launch_bounds__(256) void k3_kpinv(
    const float* __restrict__ y1, const float* __restrict__ st,
    const float* __restrict__ q_pts, const float* __restrict__ s_pts,
    const int* __restrict__ idx, const float* __restrict__ kp,
    const float* __restrict__ g_u1, const float* __restrict__ b_u1,
    const float* __restrict__ w_g1, const float* __restrict__ b_g1,
    const float* __restrict__ w_g2, const float* __restrict__ b_g2,
    float* __restrict__ x2, int M)
{
    __shared__ float a1s[32], b1s[32];
    __shared__ float wg1[32 * 8];
    __shared__ float bg1[8];
    __shared__ float wg2[8 * 30];
    __shared__ float bg2[30];
    __shared__ float kps[KP * 3];
    int t = threadIdx.x;
    if (t < 32) {
        float mean = st[t] * (1.0f / M);
        float var  = st[32 + t] * (1.0f / M) - mean * mean;
        float inv  = rsqrtf(var + EPS);
        float a = g_u1[t] * inv;
        a1s[t] = a;
        b1s[t] = b_u1[t] - mean * a;
    }
    wg1[t & 255] = w_g1[t & 255];          // 256 threads, 256 elems
    if (t < 8)   bg1[t] = b_g1[t];
    if (t < 240) wg2[t] = w_g2[t];
    if (t < 30)  bg2[t] = b_g2[t];
    if (t < KP * 3) kps[t] = kp[t];
    __syncthreads();

    int wave = t >> 6, lane = t & 63;
    int m = blockIdx.x * 4 + wave;
    if (m >= M) return;
    int part = lane >> 5;     // channel group g
    int h = lane & 31;        // neighbor

    int n = idx[m * HNB + h];
    float qx = q_pts[m * 3 + 0], qy = q_pts[m * 3 + 1], qz = q_pts[m * 3 + 2];
    float dx = s_pts[n * 3 + 0] - qx;
    float dy = s_pts[n * 3 + 1] - qy;
    float dz = s_pts[n * 3 + 2] - qz;

    // gather + BN + lrelu the 16 channels of this lane's neighbor
    float v[16];
    const float* row = y1 + (size_t)n * CMID + part * 16;
    {
        float4 f0 = ((const float4*)row)[0];
        float4 f1 = ((const float4*)row)[1];
        float4 f2 = ((const float4*)row)[2];
        float4 f3 = ((const float4*)row)[3];
        v[0]=f0.x; v[1]=f0.y; v[2]=f0.z; v[3]=f0.w;
        v[4]=f1.x; v[5]=f1.y; v[6]=f1.z; v[7]=f1.w;
        v[8]=f2.x; v[9]=f2.y; v[10]=f2.z; v[11]=f2.w;
        v[12]=f3.x; v[13]=f3.y; v[14]=f3.z; v[15]=f3.w;
    }
#pragma unroll
    for (int cc = 0; cc < 16; ++cc) {
        int c = part * 16 + cc;
        float x = v[cc] * a1s[c] + b1s[c];
        v[cc] = x >= 0.f ? x : NEG * x;
    }

    // kernel-point influences for this neighbor
    float infl[KP];
#pragma unroll
    for (int k = 0; k < KP; ++k) {
        float ex = dx - kps[k * 3 + 0];
        float ey = dy - kps[k * 3 + 1];
        float ez = dz - kps[k * 3 + 2];
        float d = sqrtf(ex * ex + ey * ey + ez * ez);
        float w = 1.0f - d;
        infl[k] = w > 0.f ? w : 0.f;
    }

    // center = max over neighbors (butterfly within each 32-lane half)
    float cmax[16];
#pragma unroll
    for (int cc = 0; cc < 16; ++cc) cmax[cc] = v[cc];
#pragma unroll
    for (int off = 1; off < 32; off <<= 1) {
#pragma unroll
        for (int cc = 0; cc < 16; ++cc) {
            float o = __shfl_xor(cmax[cc], off, 64);
            cmax[cc] = fmaxf(cmax[cc], o);
        }
    }

    // h1 = lrelu(center @ w_g1 + b_g1): each half sums its 16 channels,
    // shfl_xor(32) combines the halves.
    float h1[8];
#pragma unroll
    for (int j = 0; j < 8; ++j) {
        float acc = 0.f;
#pragma unroll
        for (int cc = 0; cc < 16; ++cc)
            acc += cmax[cc] * wg1[(part * 16 + cc) * 8 + j];
        acc += __shfl_xor(acc, 32, 64);
        acc += bg1[j];
        h1[j] = acc >= 0.f ? acc : NEG * acc;
    }

    // s = sum_k infl[k] * w[k, part]   (w from the tiny MLP, own group only)
    float s = 0.f;
#pragma unroll
    for (int k = 0; k < KP; ++k) {
        float wk = bg2[k * 2 + part];
#pragma unroll
        for (int j = 0; j < 8; ++j) wk += h1[j] * wg2[j * 30 + k * 2 + part];
        s += infl[k] * wk;
    }

    // out = sum_h v * s  (butterfly sum within each half)
#pragma unroll
    for (int cc = 0; cc < 16; ++cc) v[cc] *= s;
#pragma unroll
    for (int off = 1; off < 32; off <<= 1) {
#pragma unroll
        for (int cc = 0; cc < 16; ++cc) v[cc] += __shfl_xor(v[cc], off, 64);
    }
    if (h == 0) {
        float* o = x2 + (size_t)m * CMID + part * 16;
        ((float4*)o)[0] = make_float4(v[0], v[1], v[2], v[3]);
        ((float4*)o)[1] = make_float4(v[4], v[5], v[6], v[7]);
        ((float4*)o)[2] = make_float4(v[8], v[9], v[10], v[11]);
        ((float4*)o)[3] = make_float4(v[12], v[13], v[14], v[15]);
    }
}

// ---------------------------------------------------------------------------
// K4: per-channel sum/sumsq over x2 (32 channels) -> st[64:96), st[96:128)
// ---------------------------------------------------------------------------
__global__ __launch_bounds__(256) void k4_stats32(
    const float* __restrict__ x2, float* __restrict__ st, int M)
{
    int t = threadIdx.x;
    int c = t & 31;
    float sum = 0.f, sq = 0.f;
    for (int r = blockIdx.x * 8 + (t >> 5); r < M; r += gridDim.x * 8) {
        float v = x2[(size_t)r * CMID + c];
        sum += v; sq += v * v;
    }
    __shared__ float red[256];
    red[t] = sum; __syncthreads();
    if (t < 32) { float s = 0.f; for (int i = 0; i < 8; ++i) s += red[t + 32 * i]; atomicAdd(&st[64 + t], s); }
    __syncthreads();
    red[t] = sq; __syncthreads();
    if (t < 32) { float s = 0.f; for (int i = 0; i < 8; ++i) s += red[t + 32 * i]; atomicAdd(&st[96 + t], s); }
}

// ---------------------------------------------------------------------------
// K6: z = lrelu(bn_c(x2)) @ w_u2 computed on the fly, only stats kept:
// per-channel (128) sum/sumsq -> st[128:256), st[256:384).
// ---------------------------------------------------------------------------
__global__ __launch_bounds__(256) void k6_zstats(
    const float* __restrict__ x2, const float* __restrict__ w_u2,
    const float* __restrict__ g_c, const float* __restrict__ b_c,
    float* __restrict__ st, int M)
{
    __shared__ float Ws[CMID * CIN];   // 16 KB
    __shared__ float S[32 * CMID];     // 4 KB activated rows
    __shared__ float ac[32], bc[32];
    __shared__ float red[256];
    int t = threadIdx.x;
    for (int i = t; i < CMID * CIN; i += 256) Ws[i] = w_u2[i];
    if (t < 32) {
        float mean = st[64 + t] * (1.0f / M);
        float var  = st[96 + t] * (1.0f / M) - mean * mean;
        float inv  = rsqrtf(var + EPS);
        float a = g_c[t] * inv;
        ac[t] = a; bc[t] = b_c[t] - mean * a;
    }
    int m0 = blockIdx.x * 32;
    int rows = min(32, M - m0);
    __syncthreads();
    for (int i = t; i < rows * CMID; i += 256) {
        int c = i & 31;
        float x = x2[(size_t)m0 * CMID + i] * ac[c] + bc[c];
        S[i] = x >= 0.f ? x : NEG * x;
    }
    __syncthreads();
    int o = t & 127, r0 = t >> 7;
    float sum = 0.f, sq = 0.f;
    for (int r = r0; r < rows; r += 2) {
        float acc = 0.f;
#pragma unroll
        for (int j = 0; j < CMID; ++j) acc += S[r * CMID + j] * Ws[j * CIN + o];
        sum += acc; sq += acc * acc;
    }
    red[t] = sum; __syncthreads();
    if (t < 128) atomicAdd(&st[128 + t], red[t] + red[t + 128]);
    __syncthreads();
    red[t] = sq; __syncthreads();
    if (t < 128) atomicAdd(&st[256 + t], red[t] + red[t + 128]);
}

// ---------------------------------------------------------------------------
// K8: recompute z, apply bn_u2, add residual s_feats, lrelu -> out (M,128)
// ---------------------------------------------------------------------------
__global__ __launch_bounds__(256) void k8_final(
    const float* __restrict__ x2, const float* __restrict__ w_u2,
    const float* __restrict__ g_c, const float* __restrict__ b_c,
    const float* __restrict__ g_u2, const float* __restrict__ b_u2,
    const float* __restrict__ s_feats, const float* __restrict__ st,
    float* __restrict__ out, int M)
{
    __shared__ float Ws[CMID * CIN];
    __shared__ float S[32 * CMID];
    __shared__ float ac[32], bc[32];
    __shared__ float a2[128], b2[128];
    int t = threadIdx.x;
    for (int i = t; i < CMID * CIN; i += 256) Ws[i] = w_u2[i];
    if (t < 32) {
        float mean = st[64 + t] * (1.0f / M);
        float var  = st[96 + t] * (1.0f / M) - mean * mean;
        float inv  = rsqrtf(var + EPS);
        float a = g_c[t] * inv;
        ac[t] = a; bc[t] = b_c[t] - mean * a;
    }
    if (t < 128) {
        float mean = st[128 + t] * (1.0f / M);
        float var  = st[256 + t] * (1.0f / M) - mean * mean;
        float inv  = rsqrtf(var + EPS);
        float a = g_u2[t] * inv;
        a2[t] = a; b2[t] = b_u2[t] - mean * a;
    }
    int m0 = blockIdx.x * 32;
    int rows = min(32, M - m0);
    __syncthreads();
    for (int i = t; i < rows * CMID; i += 256) {
        int c = i & 31;
        float x = x2[(size_t)m0 * CMID + i] * ac[c] + bc[c];
        S[i] = x >= 0.f ? x : NEG * x;
    }
    __syncthreads();
    int o = t & 127, r0 = t >> 7;
    for (int r = r0; r < rows; r += 2) {
        float acc = 0.f;
#pragma unroll
        for (int j = 0; j < CMID; ++j) acc += S[r * CMID + j] * Ws[j * CIN + o];
        size_t gi = (size_t)(m0 + r) * CIN + o;
        float val = acc * a2[o] + b2[o] + s_feats[gi];
        out[gi] = val >= 0.f ? val : NEG * val;
    }
}

extern "C" void kernel_launch(void* const* d_in, const int* in_sizes, int n_in,
                              void* d_out, int out_size, void* d_ws, size_t ws_size,
                              hipStream_t stream) {
    const float* q_pts   = (const float*)d_in[0];
    const float* s_pts   = (const float*)d_in[1];
    const float* s_feats = (const float*)d_in[2];
    const int*   idx     = (const int*)d_in[3];
    const float* kp      = (const float*)d_in[4];
    const float* w_u1    = (const float*)d_in[5];
    const float* g_u1    = (const float*)d_in[6];
    const float* b_u1    = (const float*)d_in[7];
    const float* w_g1    = (const float*)d_in[8];
    const float* b_g1    = (const float*)d_in[9];
    const float* w_g2    = (const float*)d_in[10];
    const float* b_g2    = (const float*)d_in[11];
    const float* g_c     = (const float*)d_in[12];
    const float* b_c     = (const float*)d_in[13];
    const float* w_u2    = (const float*)d_in[14];
    const float* g_u2    = (const float*)d_in[15];
    const float* b_u2    = (const float*)d_in[16];

    int M = in_sizes[3] / HNB;   // 50000

    float* ws = (float*)d_ws;
    float* y1 = ws;                       // M*32
    float* x2 = ws + (size_t)M * CMID;    // M*32
    float* st = ws + (size_t)M * 2 * CMID; // 384 floats of stats

    hipMemsetAsync(st, 0, 384 * sizeof(float), stream);

    int nb = (M + 31) / 32;
    k1_gemm1<<<nb, 256, 0, stream>>>(s_feats, w_u1, y1, st, M);
    k3_kpinv<<<(M + 3) / 4, 256, 0, stream>>>(y1, st, q_pts, s_pts, idx, kp,
                                              g_u1, b_u1, w_g1, b_g1, w_g2, b_g2,
                                              x2, M);
    k4_stats32<<<128, 256, 0, stream>>>(x2, st, M);
    k6_zstats<<<nb, 256, 0, stream>>>(x2, w_u2, g_c, b_c, st, M);
    k8_final<<<nb, 256, 0, stream>>>(x2, w_u2, g_c, b_c, g_u2, b_u2,
                                     s_feats, st, (float*)d_out, M);
}